// Round 15
// baseline (2048.140 us; speedup 1.0000x reference)
//
#include <hip/hip_runtime.h>
#include <math.h>

#define B_ 256
#define T_ 200
#define H_ 256
#define DOF_ 12

typedef __bf16 bf16;
typedef __bf16 bf16x8 __attribute__((ext_vector_type(8)));
typedef float f32x4 __attribute__((ext_vector_type(4)));
typedef unsigned long long u64;

#define XK 288      // gate GEMM K: 256 h + 12 prev + 20 zero pad
#define XPAD 296
#define P1PAD 264

#define PI_D 3.14159265358979323846

// ---- workspace byte offsets (all 16B aligned) ----
#define OFF_TF     0u
#define OFF_TCONP  10400u
#define OFF_ZCP    829600u
#define OFF_H0     1878176u
#define OFF_C0     2140320u
#define OFF_WCOMB  2402464u
#define OFF_WP1    2992288u
#define OFF_WP2    3123360u
#define OFF_WO1    3131552u
#define OFF_WO2    3262624u
#define OFF_WV     3270816u
#define OFF_HX     3295392u    // 16 grps * 2 slots * 4 quarters * 64 * 4 * 16B = 512KB
#define OFF_HSEQ   3819680u    // 256*200*256*2 = 26214400 (end ~30.0MB)

__device__ __forceinline__ float sigf(float x) { return 1.f / (1.f + __expf(-x)); }
__device__ __forceinline__ float tanh_f(float x) {
  float a = fabsf(x);
  float e = __expf(-2.f * a);
  float t = (1.f - e) * __builtin_amdgcn_rcpf(1.f + e);
  return x < 0.f ? -t : t;
}

// light barrier: order LDS, leave global ops in flight
#define LBAR() asm volatile("s_waitcnt lgkmcnt(0)\n\ts_barrier" ::: "memory")

// ---------------- time features [T,13] ----------------
__global__ void k_tfeat(float* tf) {
  int i = blockIdx.x * blockDim.x + threadIdx.x;
  if (i >= T_ * 13) return;
  int t = i / 13, j = i % 13;
  float tv = (float)t / 199.f;
  float v;
  if (j == 0) v = tv;
  else {
    int k = (j - 1) >> 1;
    float f = (float)(1 << k);
    double arg = 2.0 * PI_D * (double)f * (double)tv;
    v = (j & 1) ? (float)sin(arg) : (float)cos(arg);
  }
  tf[i] = v;
}

// ------------- precompute tconp, zcp, h0, c0 (lane-packed layouts) -------------
// tconp[t*1024 + u*4 + g]  (u = global unit 0..255)
// zcp[((bid64*256 + tid)*4 + g)*4 + r]  (bid64 = quarter*16 + grp)
__global__ void k_prep(const float* __restrict__ tf, const float* __restrict__ Wih,
                       const float* __restrict__ z,
                       const float* __restrict__ bih, const float* __restrict__ bhh,
                       const float* __restrict__ Whz, const float* __restrict__ bhz,
                       const float* __restrict__ Wcz, const float* __restrict__ bcz,
                       float* tconp, float* zcp, float* h0, float* c0) {
  int i = blockIdx.x * blockDim.x + threadIdx.x;
  if (i < 204800) {
    int g = i & 3, u = (i >> 2) & 255, t = i >> 10;
    int n = g * 256 + u;
    float s = 0.f;
    #pragma unroll
    for (int j = 0; j < 13; ++j) s += tf[t * 13 + j] * Wih[n * 89 + 76 + j];
    tconp[i] = s;
    return;
  }
  i -= 204800;
  if (i < 262144) {
    int r = i & 3, g = (i >> 2) & 3, tid = (i >> 4) & 255, bid = i >> 12;
    int quarter = bid >> 4, grp = bid & 15;
    int wv = tid >> 6, ln = tid & 63, lr = ln & 15, lq = (ln >> 4) & 3;
    int b = grp * 16 + lq * 4 + r;
    int n = g * 256 + 64 * quarter + 16 * wv + lr;
    float s = bih[n] + bhh[n];
    for (int k = 0; k < 64; ++k) s += z[b * 64 + k] * Wih[n * 89 + 12 + k];
    zcp[i] = s;
    return;
  }
  i -= 262144;
  if (i < 65536) {
    int b = i / 256, u = i % 256;
    float s = bhz[u];
    for (int k = 0; k < 64; ++k) s += z[b * 64 + k] * Whz[u * 64 + k];
    h0[i] = s;
    return;
  }
  i -= 65536;
  if (i < 65536) {
    int b = i / 256, u = i % 256;
    float s = bcz[u];
    for (int k = 0; k < 64; ++k) s += z[b * 64 + k] * Wcz[u * 64 + k];
    c0[i] = s;
  }
}

// ------------- bf16 weight casts -------------
__global__ void k_cast(const float* __restrict__ Whh, const float* __restrict__ Wih,
                       const float* __restrict__ Wp1, const float* __restrict__ Wp2,
                       const float* __restrict__ Wo1, const float* __restrict__ Wo2,
                       const float* __restrict__ Wv,
                       bf16* Wcomb, bf16* Wp1b, bf16* Wp2b, bf16* Wo1b,
                       bf16* Wo2b, bf16* Wvb) {
  int i = blockIdx.x * blockDim.x + threadIdx.x;
  if (i < 294912) {
    int n = i / XK, k = i % XK;
    float v = (k < 256) ? Whh[n * 256 + k]
            : ((k < 268) ? Wih[n * 89 + (k - 256)] : 0.f);
    Wcomb[i] = (bf16)v;
    return;
  }
  i -= 294912;
  if (i < 65536) { Wp1b[i] = (bf16)Wp1[i]; return; }
  i -= 65536;
  if (i < 4096) { int r = i / 256; Wp2b[i] = (bf16)((r < 12) ? Wp2[i] : 0.f); return; }
  i -= 4096;
  if (i < 65536) { Wo1b[i] = (bf16)Wo1[i]; return; }
  i -= 65536;
  if (i < 4096) { int r = i / 256; Wo2b[i] = (bf16)((r < 3) ? Wo2[i] : 0.f); return; }
  i -= 4096;
  if (i < 12288) { int r = i / 256; Wvb[i] = (bf16)((r < 42) ? Wv[i] : 0.f); }
}

// ------- recurrent LSTM: 32 blocks = 4 quarters x 8 group-pairs -------
// Each block runs TWO batch-groups (A = 2j, B = 2j+1) interleaved so group B's
// compute hides group A's exchange RTT (and p1A/p2A hides B's). Gate weights
// (144) AND Wp1 (128) AGPR-resident; only Wp2 in LDS. 3-partner tag-embedded
// u64 relaxed agent-atomic h exchange (partners same XCD: bid % 8 == j).
__global__ __launch_bounds__(256, 1) void k_recur(
    const float* __restrict__ zcp, const float* __restrict__ tconp,
    const float* __restrict__ h0, const float* __restrict__ c0,
    const bf16* __restrict__ Wcomb, const bf16* __restrict__ Wp1b,
    const bf16* __restrict__ Wp2b,
    const float* __restrict__ bp1, const float* __restrict__ bp2,
    const float* __restrict__ jlo, const float* __restrict__ jhi,
    const float* __restrict__ ddp,
    u64* hxt,
    bf16* __restrict__ Hseq, float* __restrict__ outJ, float* __restrict__ outA) {
  __shared__ bf16 xbufA[16][XPAD];
  __shared__ bf16 xbufB[16][XPAD];
  __shared__ bf16 p1buf[16][P1PAD];
  __shared__ bf16 w2[16][P1PAD];
  const int tid = threadIdx.x;
  const int wv = tid >> 6, ln = tid & 63, lr = ln & 15, lq = ln >> 4;
  const int bid = blockIdx.x;
  const int quarter = bid >> 3, j = bid & 7;
  const int gA = 2 * j, gB = 2 * j + 1;
  const int b0A = gA * 16, b0B = gB * 16;
  const int u_gl = 64 * quarter + 16 * wv + lr;

  // ---- one-time LDS fills ----
  for (int i = tid; i < 16 * 32; i += 256) {
    int r = i >> 5, c8 = (i & 31) * 8;
    *reinterpret_cast<bf16x8*>(&w2[r][c8]) =
        *reinterpret_cast<const bf16x8*>(&Wp2b[r * 256 + c8]);
  }
  for (int i = tid; i < 16 * XPAD; i += 256) {
    int r = i / XPAD, c = i % XPAD;
    float vA = 0.f;
    if (c < 256) vA = 0.f;  // filled below per group
    if (c < 256) {
      xbufA[r][c] = (bf16)h0[(b0A + r) * 256 + c];
      xbufB[r][c] = (bf16)h0[(b0B + r) * 256 + c];
    } else if (c < 268) {
      int d = c - 256;
      float lo = jlo[d], hi = jhi[d];
      bf16 pv = (bf16)((ddp[d] - 0.5f * (hi + lo)) / (0.5f * (hi - lo)));
      xbufA[r][c] = pv;
      xbufB[r][c] = pv;
    } else {
      xbufA[r][c] = (bf16)0.f;
      xbufB[r][c] = (bf16)0.f;
    }
    (void)vA;
  }

  // ---- gate weights (quarter) -> AGPRs: 144 regs/lane ----
  f32x4 wc[4][9];
  #pragma unroll
  for (int g = 0; g < 4; ++g)
    #pragma unroll
    for (int kt = 0; kt < 9; ++kt)
      wc[g][kt] = *reinterpret_cast<const f32x4*>(
          &Wcomb[(size_t)(g * 256 + u_gl) * XK + kt * 32 + lq * 8]);
  // ---- Wp1 (wave's 64 cols) -> AGPRs: 128 regs/lane ----
  f32x4 wp[4][8];
  #pragma unroll
  for (int jn = 0; jn < 4; ++jn)
    #pragma unroll
    for (int kt = 0; kt < 8; ++kt)
      wp[jn][kt] = *reinterpret_cast<const f32x4*>(
          &Wp1b[(size_t)(64 * wv + 16 * jn + lr) * 256 + kt * 32 + lq * 8]);
  #pragma unroll
  for (int kt = 0; kt < 9; ++kt)
    asm volatile("" : "+a"(wc[0][kt]), "+a"(wc[1][kt]),
                      "+a"(wc[2][kt]), "+a"(wc[3][kt]));
  #pragma unroll
  for (int kt = 0; kt < 8; ++kt)
    asm volatile("" : "+a"(wp[0][kt]), "+a"(wp[1][kt]),
                      "+a"(wp[2][kt]), "+a"(wp[3][kt]));

  // ---- per-lane state ----
  float cA[4], cB[4];
  #pragma unroll
  for (int r = 0; r < 4; ++r) {
    cA[r] = c0[(b0A + lq * 4 + r) * 256 + u_gl];
    cB[r] = c0[(b0B + lq * 4 + r) * 256 + u_gl];
  }
  const int zc_iA = ((quarter * 16 + gA) * 256 + tid) * 16;
  const int zc_iB = ((quarter * 16 + gB) * 256 + tid) * 16;
  int tc_i = u_gl * 4;                              // += 1024 / step (shared A/B)
  int hs_iA = ((b0A + lq * 4) * T_) * 256 + u_gl;   // += 256 / step
  int hs_iB = ((b0B + lq * 4) * T_) * 256 + u_gl;
  // hx u64 offsets: (grp*8 + quarter)*512 + u_loc*8 + lq*2 ; slot stride 2048
  const int pwA = (gA * 8 + quarter) * 512 + (16 * wv + lr) * 8 + lq * 2;
  const int pwB = (gB * 8 + quarter) * 512 + (16 * wv + lr) * 8 + lq * 2;
  const int ru = tid >> 2, rlq = tid & 3;
  const int rrow0 = rlq * 4;
  const int q1 = (quarter + 1) & 3, q2 = (quarter + 2) & 3, q3 = (quarter + 3) & 3;
  const int prA1 = (gA * 8 + q1) * 512 + ru * 8 + rlq * 2;
  const int prA2 = (gA * 8 + q2) * 512 + ru * 8 + rlq * 2;
  const int prA3 = (gA * 8 + q3) * 512 + ru * 8 + rlq * 2;
  const int prB1 = (gB * 8 + q1) * 512 + ru * 8 + rlq * 2;
  const int prB2 = (gB * 8 + q2) * 512 + ru * 8 + rlq * 2;
  const int prB3 = (gB * 8 + q3) * 512 + ru * 8 + rlq * 2;
  const int col1 = 64 * q1 + ru, col2 = 64 * q2 + ru, col3 = 64 * q3 + ru;

  float bp1r[4];
  #pragma unroll
  for (int jn = 0; jn < 4; ++jn) bp1r[jn] = bp1[64 * wv + 16 * jn + lr];
  float bp2r = 0.f, ddr = 0.f, lor = -1.f, hir = 1.f;
  if (lr < 12) { bp2r = bp2[lr]; ddr = ddp[lr]; lor = jlo[lr]; hir = jhi[lr]; }
  const float jmr = 0.5f * (hir + lor), jrr = 0.5f * (hir - lor);

  __syncthreads();
  bool dead = false;

#define GATES(XB, ZCI, CREG, PWI, HSI)                                         \
  {                                                                            \
    f32x4 zc_[4], tcv_;                                                        \
    _Pragma("unroll") for (int g = 0; g < 4; ++g)                              \
        zc_[g] = *reinterpret_cast<const f32x4*>(zcp + (ZCI) + g * 4);         \
    tcv_ = *reinterpret_cast<const f32x4*>(tconp + tc_i);                      \
    f32x4 ac_[4];                                                              \
    _Pragma("unroll") for (int g = 0; g < 4; ++g)                              \
        ac_[g] = (f32x4){0.f, 0.f, 0.f, 0.f};                                  \
    _Pragma("unroll") for (int kt = 0; kt < 9; ++kt) {                         \
      bf16x8 a_ = *reinterpret_cast<const bf16x8*>(&XB[lr][kt * 32 + lq * 8]); \
      _Pragma("unroll") for (int g = 0; g < 4; ++g)                            \
          ac_[g] = __builtin_amdgcn_mfma_f32_16x16x32_bf16(                    \
              a_, __builtin_bit_cast(bf16x8, wc[g][kt]), ac_[g], 0, 0, 0);     \
    }                                                                          \
    _Pragma("unroll") for (int g = 0; g < 4; ++g) ac_[g] += zc_[g] + tcv_[g];  \
    LBAR();                                                                    \
    unsigned short s4_[4];                                                     \
    bf16 hb_[4];                                                               \
    _Pragma("unroll") for (int r = 0; r < 4; ++r) {                            \
      float cn_ = sigf(ac_[1][r]) * CREG[r] + sigf(ac_[0][r]) * tanh_f(ac_[2][r]); \
      float hn_ = sigf(ac_[3][r]) * tanh_f(cn_);                               \
      CREG[r] = cn_;                                                           \
      bf16 h_ = (bf16)hn_;                                                     \
      hb_[r] = h_;                                                             \
      s4_[r] = __builtin_bit_cast(unsigned short, h_);                         \
    }                                                                          \
    {                                                                          \
      u64 q0_ = ((u64)want << 32) | (u64)s4_[0] | ((u64)s4_[1] << 16);         \
      u64 q1_ = ((u64)want << 32) | (u64)s4_[2] | ((u64)s4_[3] << 16);         \
      int pwi_ = (PWI) + (t & 1) * 2048;                                       \
      __hip_atomic_store(hxt + pwi_, q0_, __ATOMIC_RELAXED, __HIP_MEMORY_SCOPE_AGENT); \
      __hip_atomic_store(hxt + pwi_ + 1, q1_, __ATOMIC_RELAXED, __HIP_MEMORY_SCOPE_AGENT); \
    }                                                                          \
    _Pragma("unroll") for (int r = 0; r < 4; ++r) {                            \
      XB[lq * 4 + r][u_gl] = hb_[r];                                           \
      Hseq[(HSI) + r * (T_ * 256)] = hb_[r];                                   \
    }                                                                          \
  }

#define POLLSC(XB, PR1, PR2, PR3)                                              \
  {                                                                            \
    const int so_ = (t & 1) * 2048;                                            \
    u64 pa0, pa1, pb0, pb1, pc0, pc1;                                          \
    int guard_ = 1 << 16;                                                      \
    for (;;) {                                                                 \
      pa0 = __hip_atomic_load(hxt + (PR1) + so_, __ATOMIC_RELAXED, __HIP_MEMORY_SCOPE_AGENT); \
      pa1 = __hip_atomic_load(hxt + (PR1) + so_ + 1, __ATOMIC_RELAXED, __HIP_MEMORY_SCOPE_AGENT); \
      pb0 = __hip_atomic_load(hxt + (PR2) + so_, __ATOMIC_RELAXED, __HIP_MEMORY_SCOPE_AGENT); \
      pb1 = __hip_atomic_load(hxt + (PR2) + so_ + 1, __ATOMIC_RELAXED, __HIP_MEMORY_SCOPE_AGENT); \
      pc0 = __hip_atomic_load(hxt + (PR3) + so_, __ATOMIC_RELAXED, __HIP_MEMORY_SCOPE_AGENT); \
      pc1 = __hip_atomic_load(hxt + (PR3) + so_ + 1, __ATOMIC_RELAXED, __HIP_MEMORY_SCOPE_AGENT); \
      int ok_ = ((unsigned)(pa0 >> 32) == want) & ((unsigned)(pa1 >> 32) == want) & \
                ((unsigned)(pb0 >> 32) == want) & ((unsigned)(pb1 >> 32) == want) & \
                ((unsigned)(pc0 >> 32) == want) & ((unsigned)(pc1 >> 32) == want); \
      if (__all(ok_)) break;                                                   \
      if (dead || --guard_ == 0) { dead = true; break; }                       \
    }                                                                          \
    XB[rrow0 + 0][col1] = __builtin_bit_cast(bf16, (unsigned short)(pa0));     \
    XB[rrow0 + 1][col1] = __builtin_bit_cast(bf16, (unsigned short)(pa0 >> 16)); \
    XB[rrow0 + 2][col1] = __builtin_bit_cast(bf16, (unsigned short)(pa1));     \
    XB[rrow0 + 3][col1] = __builtin_bit_cast(bf16, (unsigned short)(pa1 >> 16)); \
    XB[rrow0 + 0][col2] = __builtin_bit_cast(bf16, (unsigned short)(pb0));     \
    XB[rrow0 + 1][col2] = __builtin_bit_cast(bf16, (unsigned short)(pb0 >> 16)); \
    XB[rrow0 + 2][col2] = __builtin_bit_cast(bf16, (unsigned short)(pb1));     \
    XB[rrow0 + 3][col2] = __builtin_bit_cast(bf16, (unsigned short)(pb1 >> 16)); \
    XB[rrow0 + 0][col3] = __builtin_bit_cast(bf16, (unsigned short)(pc0));     \
    XB[rrow0 + 1][col3] = __builtin_bit_cast(bf16, (unsigned short)(pc0 >> 16)); \
    XB[rrow0 + 2][col3] = __builtin_bit_cast(bf16, (unsigned short)(pc1));     \
    XB[rrow0 + 3][col3] = __builtin_bit_cast(bf16, (unsigned short)(pc1 >> 16)); \
  }

#define HEADS(XB, CURQ, B0, HALFSEL)                                           \
  {                                                                            \
    f32x4 pa_[4];                                                              \
    _Pragma("unroll") for (int jn = 0; jn < 4; ++jn)                           \
        pa_[jn] = (f32x4){bp1r[jn], bp1r[jn], bp1r[jn], bp1r[jn]};             \
    _Pragma("unroll") for (int kt = 0; kt < 8; ++kt) {                         \
      bf16x8 av_ = *reinterpret_cast<const bf16x8*>(&XB[lr][kt * 32 + lq * 8]); \
      _Pragma("unroll") for (int jn = 0; jn < 4; ++jn)                         \
          pa_[jn] = __builtin_amdgcn_mfma_f32_16x16x32_bf16(                   \
              av_, __builtin_bit_cast(bf16x8, wp[jn][kt]), pa_[jn], 0, 0, 0);  \
    }                                                                          \
    _Pragma("unroll") for (int jn = 0; jn < 4; ++jn)                           \
        _Pragma("unroll") for (int r = 0; r < 4; ++r)                          \
            p1buf[lq * 4 + r][64 * wv + 16 * jn + lr] = (bf16)fmaxf(pa_[jn][r], 0.f); \
    LBAR();                                                                    \
    if (wv == 0) {                                                             \
      f32x4 acc_ = {0.f, 0.f, 0.f, 0.f};                                       \
      _Pragma("unroll") for (int kt = 0; kt < 8; ++kt) {                       \
        bf16x8 ap_ = *reinterpret_cast<const bf16x8*>(&p1buf[lr][kt * 32 + lq * 8]); \
        bf16x8 w2_ = *reinterpret_cast<const bf16x8*>(&w2[lr][kt * 32 + lq * 8]); \
        acc_ = __builtin_amdgcn_mfma_f32_16x16x32_bf16(ap_, w2_, acc_, 0, 0, 0); \
      }                                                                        \
      if (lr < 12) {                                                           \
        _Pragma("unroll") for (int r = 0; r < 4; ++r) {                        \
          int b_ = lq * 4 + r;                                                 \
          float act_ = tanh_f(acc_[r] + bp2r);                                 \
          float curp_ = act_ * 0.25f + ddr;                                    \
          float cl_ = fminf(fmaxf(curp_, lor), hir);                           \
          if (quarter == 0) {                                                  \
            size_t o_ = ((size_t)((B0) + b_) * T_ + t) * 12 + lr;              \
            outA[o_] = act_;                                                   \
            outJ[o_] = curp_;                                                  \
          }                                                                    \
          XB[b_][256 + lr] = (bf16)((cl_ - jmr) / jrr);                        \
        }                                                                      \
      }                                                                        \
    }                                                                          \
  }

  for (int t = 0; t < T_; ++t) {
    const unsigned int want = t + 1;
    // re-pin AGPR weights once per iteration
    #pragma unroll
    for (int kt = 0; kt < 9; ++kt)
      asm volatile("" : "+a"(wc[0][kt]), "+a"(wc[1][kt]),
                        "+a"(wc[2][kt]), "+a"(wc[3][kt]));
    #pragma unroll
    for (int kt = 0; kt < 8; ++kt)
      asm volatile("" : "+a"(wp[0][kt]), "+a"(wp[1][kt]),
                        "+a"(wp[2][kt]), "+a"(wp[3][kt]));

    GATES(xbufA, zc_iA, cA, pwA, hs_iA)          // publish A
    GATES(xbufB, zc_iB, cB, pwB, hs_iB)          // publish B (covers A's RTT)
    POLLSC(xbufA, prA1, prA2, prA3)              // A partner h -> xbufA
    LBAR();                                      // full h_A visible
    HEADS(xbufA, quarter, b0A, 0)                // p1A + p2A (covers B's RTT)
    POLLSC(xbufB, prB1, prB2, prB3)              // B partner h -> xbufB
    LBAR();                                      // full h_B + prev_normA visible
    HEADS(xbufB, quarter, b0B, 1)                // p1B + p2B
    LBAR();                                      // prev_normB visible
    tc_i += 1024;
    hs_iA += 256;
    hs_iB += 256;
  }
#undef GATES
#undef POLLSC
#undef HEADS
}

// ------------- post pass: obj head, sigma head, FK, normalize -------------
__global__ __launch_bounds__(256) void k_post(
    const bf16* __restrict__ Hseq, const bf16* __restrict__ Wo1b,
    const bf16* __restrict__ Wo2b, const bf16* __restrict__ Wvb,
    const float* __restrict__ bo1, const float* __restrict__ bo2,
    const float* __restrict__ bv,
    const float* __restrict__ Wfk, const float* __restrict__ bfk,
    const float* __restrict__ pm, const float* __restrict__ ps,
    const float* __restrict__ joints, float* __restrict__ out0,
    float* __restrict__ out3) {
  __shared__ bf16 u1buf[16][P1PAD];
  __shared__ float objbuf[16][3];
  __shared__ float jbuf[16][12];
  const int tid = threadIdx.x;
  const int wv = tid >> 6;
  const int ln = tid & 63;
  const int lr = ln & 15;
  const int lq = ln >> 4;

  bf16x8 wo1f[4][8];
  float bo1r[4];
  #pragma unroll
  for (int jn = 0; jn < 4; ++jn) {
    int n0 = wv * 64 + jn * 16;
    bo1r[jn] = bo1[n0 + lr];
    #pragma unroll
    for (int kt = 0; kt < 8; ++kt)
      wo1f[jn][kt] = *reinterpret_cast<const bf16x8*>(
          &Wo1b[(size_t)(n0 + lr) * 256 + kt * 32 + lq * 8]);
  }
  const int col = (wv - 1) * 16 + lr;
  bf16x8 wvf[8];
  float bvr = 0.f;
  if (wv >= 1) {
    #pragma unroll
    for (int kt = 0; kt < 8; ++kt)
      wvf[kt] = *reinterpret_cast<const bf16x8*>(
          &Wvb[(size_t)col * 256 + kt * 32 + lq * 8]);
    bvr = (col < 42) ? bv[col] : 0.f;
  }
  bf16x8 wo2f[8];
  if (wv == 0) {
    #pragma unroll
    for (int kt = 0; kt < 8; ++kt)
      wo2f[kt] = *reinterpret_cast<const bf16x8*>(
          &Wo2b[(size_t)lr * 256 + kt * 32 + lq * 8]);
  }

  for (int it = 0; it < 10; ++it) {
    int tt = blockIdx.x * 10 + it;
    size_t r0 = (size_t)tt * 16;
    bf16x8 ah[8];
    #pragma unroll
    for (int kt = 0; kt < 8; ++kt)
      ah[kt] = *reinterpret_cast<const bf16x8*>(&Hseq[(r0 + lr) * 256 + kt * 32 + lq * 8]);
    #pragma unroll
    for (int jn = 0; jn < 4; ++jn) {
      int n0 = wv * 64 + jn * 16;
      float bb = bo1r[jn];
      f32x4 acc = {bb, bb, bb, bb};
      #pragma unroll
      for (int kt = 0; kt < 8; ++kt)
        acc = __builtin_amdgcn_mfma_f32_16x16x32_bf16(ah[kt], wo1f[jn][kt], acc, 0, 0, 0);
      #pragma unroll
      for (int r = 0; r < 4; ++r)
        u1buf[lq * 4 + r][n0 + lr] = (bf16)fmaxf(acc[r], 0.f);
    }
    if (wv >= 1) {
      f32x4 acc = {bvr, bvr, bvr, bvr};
      #pragma unroll
      for (int kt = 0; kt < 8; ++kt)
        acc = __builtin_amdgcn_mfma_f32_16x16x32_bf16(ah[kt], wvf[kt], acc, 0, 0, 0);
      if (col < 42) {
        #pragma unroll
        for (int r = 0; r < 4; ++r) {
          float s = 0.05f + 0.45f * sigf(acc[r]);
          out3[(r0 + lq * 4 + r) * 42 + col] = __logf(s);
        }
      }
    }
    if (tid < 192) {
      int rr = tid / 12, d = tid % 12;
      jbuf[rr][d] = joints[(r0 + rr) * 12 + d];
    }
    __syncthreads();
    if (wv == 0) {
      bf16x8 ap[8];
      #pragma unroll
      for (int kt = 0; kt < 8; ++kt)
        ap[kt] = *reinterpret_cast<const bf16x8*>(&u1buf[lr][kt * 32 + lq * 8]);
      f32x4 acc = {0.f, 0.f, 0.f, 0.f};
      #pragma unroll
      for (int kt = 0; kt < 8; ++kt)
        acc = __builtin_amdgcn_mfma_f32_16x16x32_bf16(ap[kt], wo2f[kt], acc, 0, 0, 0);
      if (lr < 3) {
        #pragma unroll
        for (int r = 0; r < 4; ++r)
          objbuf[lq * 4 + r][lr] = acc[r] + bo2[lr];
      }
    }
    __syncthreads();
    for (int e = tid; e < 16 * 42; e += 256) {
      int rr = e / 42, pd = e % 42;
      float v;
      if (pd < 39) {
        float s = bfk[pd];
        #pragma unroll
        for (int d = 0; d < 12; ++d) s += jbuf[rr][d] * Wfk[pd * 12 + d];
        v = s;
      } else v = objbuf[rr][pd - 39];
      out0[(r0 + rr) * 42 + pd] = (v - pm[pd]) / ps[pd];
    }
    __syncthreads();
  }
}

extern "C" void kernel_launch(void* const* d_in, const int* in_sizes, int n_in,
                              void* d_out, int out_size, void* d_ws, size_t ws_size,
                              hipStream_t stream) {
  const float* z   = (const float*)d_in[0];
  const float* Whz = (const float*)d_in[1];
  const float* bhz = (const float*)d_in[2];
  const float* Wcz = (const float*)d_in[3];
  const float* bcz = (const float*)d_in[4];
  const float* Wih = (const float*)d_in[5];
  const float* Whh = (const float*)d_in[6];
  const float* bih = (const float*)d_in[7];
  const float* bhh = (const float*)d_in[8];
  const float* Wp1 = (const float*)d_in[9];
  const float* bp1 = (const float*)d_in[10];
  const float* Wp2 = (const float*)d_in[11];
  const float* bp2 = (const float*)d_in[12];
  const float* Wo1 = (const float*)d_in[13];
  const float* bo1 = (const float*)d_in[14];
  const float* Wo2 = (const float*)d_in[15];
  const float* bo2 = (const float*)d_in[16];
  const float* Wv  = (const float*)d_in[17];
  const float* bv  = (const float*)d_in[18];
  const float* Wfk = (const float*)d_in[19];
  const float* bfk = (const float*)d_in[20];
  const float* pm  = (const float*)d_in[21];
  const float* ps  = (const float*)d_in[22];
  const float* jlo = (const float*)d_in[23];
  const float* jhi = (const float*)d_in[24];
  const float* ddp = (const float*)d_in[25];

  char* ws = (char*)d_ws;
  float* tf    = (float*)(ws + OFF_TF);
  float* tconp = (float*)(ws + OFF_TCONP);
  float* zcp   = (float*)(ws + OFF_ZCP);
  float* h0    = (float*)(ws + OFF_H0);
  float* c0    = (float*)(ws + OFF_C0);
  bf16* Wcomb  = (bf16*)(ws + OFF_WCOMB);
  bf16* Wp1b   = (bf16*)(ws + OFF_WP1);
  bf16* Wp2b   = (bf16*)(ws + OFF_WP2);
  bf16* Wo1b   = (bf16*)(ws + OFF_WO1);
  bf16* Wo2b   = (bf16*)(ws + OFF_WO2);
  bf16* Wvb    = (bf16*)(ws + OFF_WV);
  u64* hxt     = (u64*)(ws + OFF_HX);
  bf16* Hseq   = (bf16*)(ws + OFF_HSEQ);

  float* out  = (float*)d_out;
  float* out0 = out;                 // graph_x_mu [B,T,42]
  float* outJ = out + 2150400;       // joint_traj [B,T,12]
  float* outA = out + 2764800;       // actions    [B,T,12]
  float* out3 = out + 3379200;       // log_sigma  [B,T,42]

  k_tfeat<<<11, 256, 0, stream>>>(tf);
  k_prep<<<2336, 256, 0, stream>>>(tf, Wih, z, bih, bhh, Whz, bhz, Wcz, bcz,
                                   tconp, zcp, h0, c0);
  k_cast<<<1744, 256, 0, stream>>>(Whh, Wih, Wp1, Wp2, Wo1, Wo2, Wv,
                                   Wcomb, Wp1b, Wp2b, Wo1b, Wo2b, Wvb);
  k_recur<<<32, 256, 0, stream>>>(zcp, tconp, h0, c0, Wcomb, Wp1b, Wp2b,
                                  bp1, bp2, jlo, jhi, ddp, hxt,
                                  Hseq, outJ, outA);
  k_post<<<320, 256, 0, stream>>>(Hseq, Wo1b, Wo2b, Wvb, bo1, bo2, bv,
                                  Wfk, bfk, pm, ps, outJ, out0, out3);
}

// Round 16
// 1429.122 us; speedup vs baseline: 1.4331x; 1.4331x over previous
//
#include <hip/hip_runtime.h>
#include <math.h>

#define B_ 256
#define T_ 200
#define H_ 256
#define DOF_ 12

typedef __bf16 bf16;
typedef __bf16 bf16x8 __attribute__((ext_vector_type(8)));
typedef float f32x4 __attribute__((ext_vector_type(4)));
typedef unsigned long long u64;

#define XK 288      // gate GEMM K: 256 h + 12 prev + 20 zero pad
#define XPAD 296
#define P1PAD 264

#define PI_D 3.14159265358979323846

// ---- workspace byte offsets (all 16B aligned) ----
#define OFF_TF     0u
#define OFF_TCONP  10400u
#define OFF_ZCP    829600u
#define OFF_H0     1878176u
#define OFF_C0     2140320u
#define OFF_WCOMB  2402464u
#define OFF_WP1    2992288u
#define OFF_WP2    3123360u
#define OFF_WO1    3131552u
#define OFF_WO2    3262624u
#define OFF_WV     3270816u
#define OFF_HX     3295392u    // 16 grps * 2 slots * 4 quarters * 64 * 4 * 16B = 512KB
#define OFF_HSEQ   3819680u    // 256*200*256*2 = 26214400 (end ~30.0MB)

__device__ __forceinline__ float sigf(float x) { return 1.f / (1.f + __expf(-x)); }
__device__ __forceinline__ float tanh_f(float x) {
  float a = fabsf(x);
  float e = __expf(-2.f * a);
  float t = (1.f - e) * __builtin_amdgcn_rcpf(1.f + e);
  return x < 0.f ? -t : t;
}

// light barrier: order LDS, leave global ops in flight
#define LBAR() asm volatile("s_waitcnt lgkmcnt(0)\n\ts_barrier" ::: "memory")

// ---------------- time features [T,13] ----------------
__global__ void k_tfeat(float* tf) {
  int i = blockIdx.x * blockDim.x + threadIdx.x;
  if (i >= T_ * 13) return;
  int t = i / 13, j = i % 13;
  float tv = (float)t / 199.f;
  float v;
  if (j == 0) v = tv;
  else {
    int k = (j - 1) >> 1;
    float f = (float)(1 << k);
    double arg = 2.0 * PI_D * (double)f * (double)tv;
    v = (j & 1) ? (float)sin(arg) : (float)cos(arg);
  }
  tf[i] = v;
}

// ------------- precompute tconp, zcp, h0, c0 (lane-packed layouts) -------------
// tconp[t*1024 + u*4 + g]  (u = global unit 0..255)
// zcp[((bid64*256 + tid)*4 + g)*4 + r]  (bid64 = quarter*16 + grp)
__global__ void k_prep(const float* __restrict__ tf, const float* __restrict__ Wih,
                       const float* __restrict__ z,
                       const float* __restrict__ bih, const float* __restrict__ bhh,
                       const float* __restrict__ Whz, const float* __restrict__ bhz,
                       const float* __restrict__ Wcz, const float* __restrict__ bcz,
                       float* tconp, float* zcp, float* h0, float* c0) {
  int i = blockIdx.x * blockDim.x + threadIdx.x;
  if (i < 204800) {
    int g = i & 3, u = (i >> 2) & 255, t = i >> 10;
    int n = g * 256 + u;
    float s = 0.f;
    #pragma unroll
    for (int j = 0; j < 13; ++j) s += tf[t * 13 + j] * Wih[n * 89 + 76 + j];
    tconp[i] = s;
    return;
  }
  i -= 204800;
  if (i < 262144) {
    int r = i & 3, g = (i >> 2) & 3, tid = (i >> 4) & 255, bid = i >> 12;
    int quarter = bid >> 4, grp = bid & 15;
    int wv = tid >> 6, ln = tid & 63, lr = ln & 15, lq = (ln >> 4) & 3;
    int b = grp * 16 + lq * 4 + r;
    int n = g * 256 + 64 * quarter + 16 * wv + lr;
    float s = bih[n] + bhh[n];
    for (int k = 0; k < 64; ++k) s += z[b * 64 + k] * Wih[n * 89 + 12 + k];
    zcp[i] = s;
    return;
  }
  i -= 262144;
  if (i < 65536) {
    int b = i / 256, u = i % 256;
    float s = bhz[u];
    for (int k = 0; k < 64; ++k) s += z[b * 64 + k] * Whz[u * 64 + k];
    h0[i] = s;
    return;
  }
  i -= 65536;
  if (i < 65536) {
    int b = i / 256, u = i % 256;
    float s = bcz[u];
    for (int k = 0; k < 64; ++k) s += z[b * 64 + k] * Wcz[u * 64 + k];
    c0[i] = s;
  }
}

// ------------- bf16 weight casts -------------
__global__ void k_cast(const float* __restrict__ Whh, const float* __restrict__ Wih,
                       const float* __restrict__ Wp1, const float* __restrict__ Wp2,
                       const float* __restrict__ Wo1, const float* __restrict__ Wo2,
                       const float* __restrict__ Wv,
                       bf16* Wcomb, bf16* Wp1b, bf16* Wp2b, bf16* Wo1b,
                       bf16* Wo2b, bf16* Wvb) {
  int i = blockIdx.x * blockDim.x + threadIdx.x;
  if (i < 294912) {
    int n = i / XK, k = i % XK;
    float v = (k < 256) ? Whh[n * 256 + k]
            : ((k < 268) ? Wih[n * 89 + (k - 256)] : 0.f);
    Wcomb[i] = (bf16)v;
    return;
  }
  i -= 294912;
  if (i < 65536) { Wp1b[i] = (bf16)Wp1[i]; return; }
  i -= 65536;
  if (i < 4096) { int r = i / 256; Wp2b[i] = (bf16)((r < 12) ? Wp2[i] : 0.f); return; }
  i -= 4096;
  if (i < 65536) { Wo1b[i] = (bf16)Wo1[i]; return; }
  i -= 65536;
  if (i < 4096) { int r = i / 256; Wo2b[i] = (bf16)((r < 3) ? Wo2[i] : 0.f); return; }
  i -= 4096;
  if (i < 12288) { int r = i / 256; Wvb[i] = (bf16)((r < 42) ? Wv[i] : 0.f); }
}

// ------- recurrent LSTM: 32 blocks = 4 quarters x 8 group-pairs -------
// Each block runs TWO batch-groups (A = 2j, B = 2j+1) interleaved so group B's
// gates+elem and group A's heads hide the exchange visibility latency.
// Gate weights (144) in AGPRs; Wp1 in LDS; Wp2 in per-thread VGPRs.
// 3-partner tag-embedded u64 relaxed agent-atomic h exchange.
__global__ __launch_bounds__(256, 1) void k_recur(
    const float* __restrict__ zcp, const float* __restrict__ tconp,
    const float* __restrict__ h0, const float* __restrict__ c0,
    const bf16* __restrict__ Wcomb, const bf16* __restrict__ Wp1b,
    const bf16* __restrict__ Wp2b,
    const float* __restrict__ bp1, const float* __restrict__ bp2,
    const float* __restrict__ jlo, const float* __restrict__ jhi,
    const float* __restrict__ ddp,
    u64* hxt,
    bf16* __restrict__ Hseq, float* __restrict__ outJ, float* __restrict__ outA) {
  __shared__ bf16 xbufA[16][XPAD];
  __shared__ bf16 xbufB[16][XPAD];
  __shared__ bf16 w1[256][P1PAD];      // Wp1 only
  __shared__ bf16 p1buf[16][P1PAD];
  const int tid = threadIdx.x;
  const int wv = tid >> 6, ln = tid & 63, lr = ln & 15, lq = ln >> 4;
  const int bid = blockIdx.x;
  const int quarter = bid >> 3, j = bid & 7;
  const int gA = 2 * j, gB = 2 * j + 1;
  const int b0A = gA * 16, b0B = gB * 16;
  const int u_gl = 64 * quarter + 16 * wv + lr;

  // ---- one-time LDS fills ----
  for (int i = tid; i < 256 * 32; i += 256) {
    int r = i >> 5, c8 = (i & 31) * 8;
    *reinterpret_cast<bf16x8*>(&w1[r][c8]) =
        *reinterpret_cast<const bf16x8*>(&Wp1b[r * 256 + c8]);
  }
  for (int i = tid; i < 16 * XPAD; i += 256) {
    int r = i / XPAD, c = i % XPAD;
    if (c < 256) {
      xbufA[r][c] = (bf16)h0[(b0A + r) * 256 + c];
      xbufB[r][c] = (bf16)h0[(b0B + r) * 256 + c];
    } else if (c < 268) {
      int d = c - 256;
      float lo = jlo[d], hi = jhi[d];
      bf16 pv = (bf16)((ddp[d] - 0.5f * (hi + lo)) / (0.5f * (hi - lo)));
      xbufA[r][c] = pv;
      xbufB[r][c] = pv;
    } else {
      xbufA[r][c] = (bf16)0.f;
      xbufB[r][c] = (bf16)0.f;
    }
  }

  // ---- gate weights (quarter) -> AGPRs: 144 regs/lane ----
  f32x4 wc[4][9];
  #pragma unroll
  for (int g = 0; g < 4; ++g)
    #pragma unroll
    for (int kt = 0; kt < 9; ++kt)
      wc[g][kt] = *reinterpret_cast<const f32x4*>(
          &Wcomb[(size_t)(g * 256 + u_gl) * XK + kt * 32 + lq * 8]);
  #pragma unroll
  for (int kt = 0; kt < 9; ++kt)
    asm volatile("" : "+a"(wc[0][kt]), "+a"(wc[1][kt]),
                      "+a"(wc[2][kt]), "+a"(wc[3][kt]));
  // ---- Wp2 row lr -> per-thread VGPRs (used by wave 0 only) ----
  bf16x8 w2r[8];
  #pragma unroll
  for (int kt = 0; kt < 8; ++kt)
    w2r[kt] = *reinterpret_cast<const bf16x8*>(&Wp2b[lr * 256 + kt * 32 + lq * 8]);

  // ---- per-lane state ----
  float cA[4], cB[4];
  #pragma unroll
  for (int r = 0; r < 4; ++r) {
    cA[r] = c0[(b0A + lq * 4 + r) * 256 + u_gl];
    cB[r] = c0[(b0B + lq * 4 + r) * 256 + u_gl];
  }
  const int zc_iA = ((quarter * 16 + gA) * 256 + tid) * 16;
  const int zc_iB = ((quarter * 16 + gB) * 256 + tid) * 16;
  int tc_i = u_gl * 4;                              // += 1024 / step (shared A/B)
  int hs_iA = ((b0A + lq * 4) * T_) * 256 + u_gl;   // += 256 / step
  int hs_iB = ((b0B + lq * 4) * T_) * 256 + u_gl;
  const int pwA = (gA * 8 + quarter) * 512 + (16 * wv + lr) * 8 + lq * 2;
  const int pwB = (gB * 8 + quarter) * 512 + (16 * wv + lr) * 8 + lq * 2;
  const int ru = tid >> 2, rlq = tid & 3;
  const int rrow0 = rlq * 4;
  const int q1 = (quarter + 1) & 3, q2 = (quarter + 2) & 3, q3 = (quarter + 3) & 3;
  const int prA1 = (gA * 8 + q1) * 512 + ru * 8 + rlq * 2;
  const int prA2 = (gA * 8 + q2) * 512 + ru * 8 + rlq * 2;
  const int prA3 = (gA * 8 + q3) * 512 + ru * 8 + rlq * 2;
  const int prB1 = (gB * 8 + q1) * 512 + ru * 8 + rlq * 2;
  const int prB2 = (gB * 8 + q2) * 512 + ru * 8 + rlq * 2;
  const int prB3 = (gB * 8 + q3) * 512 + ru * 8 + rlq * 2;
  const int col1 = 64 * q1 + ru, col2 = 64 * q2 + ru, col3 = 64 * q3 + ru;

  float bp1r[4];
  #pragma unroll
  for (int jn = 0; jn < 4; ++jn) bp1r[jn] = bp1[64 * wv + 16 * jn + lr];
  float bp2r = 0.f, ddr = 0.f, lor = -1.f, hir = 1.f;
  if (lr < 12) { bp2r = bp2[lr]; ddr = ddp[lr]; lor = jlo[lr]; hir = jhi[lr]; }
  const float jmr = 0.5f * (hir + lor), jrr = 0.5f * (hir - lor);

  __syncthreads();
  bool dead = false;

#define GATES(XB, ZCI, CREG, PWI, HSI)                                         \
  {                                                                            \
    f32x4 zc_[4], tcv_;                                                        \
    _Pragma("unroll") for (int g = 0; g < 4; ++g)                              \
        zc_[g] = *reinterpret_cast<const f32x4*>(zcp + (ZCI) + g * 4);         \
    tcv_ = *reinterpret_cast<const f32x4*>(tconp + tc_i);                      \
    f32x4 ac_[4];                                                              \
    _Pragma("unroll") for (int g = 0; g < 4; ++g)                              \
        ac_[g] = (f32x4){0.f, 0.f, 0.f, 0.f};                                  \
    _Pragma("unroll") for (int kt = 0; kt < 9; ++kt) {                         \
      bf16x8 a_ = *reinterpret_cast<const bf16x8*>(&XB[lr][kt * 32 + lq * 8]); \
      _Pragma("unroll") for (int g = 0; g < 4; ++g)                            \
          ac_[g] = __builtin_amdgcn_mfma_f32_16x16x32_bf16(                    \
              a_, __builtin_bit_cast(bf16x8, wc[g][kt]), ac_[g], 0, 0, 0);     \
    }                                                                          \
    _Pragma("unroll") for (int g = 0; g < 4; ++g) ac_[g] += zc_[g] + tcv_[g];  \
    LBAR();                                                                    \
    unsigned short s4_[4];                                                     \
    bf16 hb_[4];                                                               \
    _Pragma("unroll") for (int r = 0; r < 4; ++r) {                            \
      float cn_ = sigf(ac_[1][r]) * CREG[r] + sigf(ac_[0][r]) * tanh_f(ac_[2][r]); \
      float hn_ = sigf(ac_[3][r]) * tanh_f(cn_);                               \
      CREG[r] = cn_;                                                           \
      bf16 h_ = (bf16)hn_;                                                     \
      hb_[r] = h_;                                                             \
      s4_[r] = __builtin_bit_cast(unsigned short, h_);                         \
    }                                                                          \
    {                                                                          \
      u64 q0_ = ((u64)want << 32) | (u64)s4_[0] | ((u64)s4_[1] << 16);         \
      u64 q1_ = ((u64)want << 32) | (u64)s4_[2] | ((u64)s4_[3] << 16);         \
      int pwi_ = (PWI) + (t & 1) * 2048;                                       \
      __hip_atomic_store(hxt + pwi_, q0_, __ATOMIC_RELAXED, __HIP_MEMORY_SCOPE_AGENT); \
      __hip_atomic_store(hxt + pwi_ + 1, q1_, __ATOMIC_RELAXED, __HIP_MEMORY_SCOPE_AGENT); \
    }                                                                          \
    _Pragma("unroll") for (int r = 0; r < 4; ++r) {                            \
      XB[lq * 4 + r][u_gl] = hb_[r];                                           \
      Hseq[(HSI) + r * (T_ * 256)] = hb_[r];                                   \
    }                                                                          \
  }

#define POLLSC(XB, PR1, PR2, PR3)                                              \
  {                                                                            \
    const int so_ = (t & 1) * 2048;                                            \
    u64 pa0, pa1, pb0, pb1, pc0, pc1;                                          \
    int guard_ = 1 << 16;                                                      \
    for (;;) {                                                                 \
      pa0 = __hip_atomic_load(hxt + (PR1) + so_, __ATOMIC_RELAXED, __HIP_MEMORY_SCOPE_AGENT); \
      pa1 = __hip_atomic_load(hxt + (PR1) + so_ + 1, __ATOMIC_RELAXED, __HIP_MEMORY_SCOPE_AGENT); \
      pb0 = __hip_atomic_load(hxt + (PR2) + so_, __ATOMIC_RELAXED, __HIP_MEMORY_SCOPE_AGENT); \
      pb1 = __hip_atomic_load(hxt + (PR2) + so_ + 1, __ATOMIC_RELAXED, __HIP_MEMORY_SCOPE_AGENT); \
      pc0 = __hip_atomic_load(hxt + (PR3) + so_, __ATOMIC_RELAXED, __HIP_MEMORY_SCOPE_AGENT); \
      pc1 = __hip_atomic_load(hxt + (PR3) + so_ + 1, __ATOMIC_RELAXED, __HIP_MEMORY_SCOPE_AGENT); \
      int ok_ = ((unsigned)(pa0 >> 32) == want) & ((unsigned)(pa1 >> 32) == want) & \
                ((unsigned)(pb0 >> 32) == want) & ((unsigned)(pb1 >> 32) == want) & \
                ((unsigned)(pc0 >> 32) == want) & ((unsigned)(pc1 >> 32) == want); \
      if (__all(ok_)) break;                                                   \
      if (dead || --guard_ == 0) { dead = true; break; }                       \
    }                                                                          \
    XB[rrow0 + 0][col1] = __builtin_bit_cast(bf16, (unsigned short)(pa0));     \
    XB[rrow0 + 1][col1] = __builtin_bit_cast(bf16, (unsigned short)(pa0 >> 16)); \
    XB[rrow0 + 2][col1] = __builtin_bit_cast(bf16, (unsigned short)(pa1));     \
    XB[rrow0 + 3][col1] = __builtin_bit_cast(bf16, (unsigned short)(pa1 >> 16)); \
    XB[rrow0 + 0][col2] = __builtin_bit_cast(bf16, (unsigned short)(pb0));     \
    XB[rrow0 + 1][col2] = __builtin_bit_cast(bf16, (unsigned short)(pb0 >> 16)); \
    XB[rrow0 + 2][col2] = __builtin_bit_cast(bf16, (unsigned short)(pb1));     \
    XB[rrow0 + 3][col2] = __builtin_bit_cast(bf16, (unsigned short)(pb1 >> 16)); \
    XB[rrow0 + 0][col3] = __builtin_bit_cast(bf16, (unsigned short)(pc0));     \
    XB[rrow0 + 1][col3] = __builtin_bit_cast(bf16, (unsigned short)(pc0 >> 16)); \
    XB[rrow0 + 2][col3] = __builtin_bit_cast(bf16, (unsigned short)(pc1));     \
    XB[rrow0 + 3][col3] = __builtin_bit_cast(bf16, (unsigned short)(pc1 >> 16)); \
  }

#define HEADS(XB, B0)                                                          \
  {                                                                            \
    f32x4 pa_[4];                                                              \
    _Pragma("unroll") for (int jn = 0; jn < 4; ++jn)                           \
        pa_[jn] = (f32x4){bp1r[jn], bp1r[jn], bp1r[jn], bp1r[jn]};             \
    _Pragma("unroll") for (int kt = 0; kt < 8; ++kt) {                         \
      bf16x8 av_ = *reinterpret_cast<const bf16x8*>(&XB[lr][kt * 32 + lq * 8]); \
      _Pragma("unroll") for (int jn = 0; jn < 4; ++jn) {                       \
        bf16x8 bv_ = *reinterpret_cast<const bf16x8*>(                         \
            &w1[64 * wv + 16 * jn + lr][kt * 32 + lq * 8]);                    \
        pa_[jn] = __builtin_amdgcn_mfma_f32_16x16x32_bf16(av_, bv_, pa_[jn], 0, 0, 0); \
      }                                                                        \
    }                                                                          \
    _Pragma("unroll") for (int jn = 0; jn < 4; ++jn)                           \
        _Pragma("unroll") for (int r = 0; r < 4; ++r)                          \
            p1buf[lq * 4 + r][64 * wv + 16 * jn + lr] = (bf16)fmaxf(pa_[jn][r], 0.f); \
    LBAR();                                                                    \
    if (wv == 0) {                                                             \
      f32x4 acc_ = {0.f, 0.f, 0.f, 0.f};                                       \
      _Pragma("unroll") for (int kt = 0; kt < 8; ++kt) {                       \
        bf16x8 ap_ = *reinterpret_cast<const bf16x8*>(&p1buf[lr][kt * 32 + lq * 8]); \
        acc_ = __builtin_amdgcn_mfma_f32_16x16x32_bf16(ap_, w2r[kt], acc_, 0, 0, 0); \
      }                                                                        \
      if (lr < 12) {                                                           \
        _Pragma("unroll") for (int r = 0; r < 4; ++r) {                        \
          int b_ = lq * 4 + r;                                                 \
          float act_ = tanh_f(acc_[r] + bp2r);                                 \
          float curp_ = act_ * 0.25f + ddr;                                    \
          float cl_ = fminf(fmaxf(curp_, lor), hir);                           \
          if (quarter == 0) {                                                  \
            size_t o_ = ((size_t)((B0) + b_) * T_ + t) * 12 + lr;              \
            outA[o_] = act_;                                                   \
            outJ[o_] = curp_;                                                  \
          }                                                                    \
          XB[b_][256 + lr] = (bf16)((cl_ - jmr) / jrr);                        \
        }                                                                      \
      }                                                                        \
    }                                                                          \
  }

  for (int t = 0; t < T_; ++t) {
    const unsigned int want = t + 1;
    #pragma unroll
    for (int kt = 0; kt < 9; ++kt)
      asm volatile("" : "+a"(wc[0][kt]), "+a"(wc[1][kt]),
                        "+a"(wc[2][kt]), "+a"(wc[3][kt]));

    GATES(xbufA, zc_iA, cA, pwA, hs_iA)          // publish A
    GATES(xbufB, zc_iB, cB, pwB, hs_iB)          // publish B (covers A's RTT)
    POLLSC(xbufA, prA1, prA2, prA3)              // A partner h -> xbufA
    LBAR();                                      // full h_A visible
    HEADS(xbufA, b0A)                            // p1A + p2A (covers B's RTT)
    POLLSC(xbufB, prB1, prB2, prB3)              // B partner h -> xbufB
    LBAR();                                      // full h_B + prev_normA visible
    HEADS(xbufB, b0B)                            // p1B + p2B
    LBAR();                                      // prev_normB visible
    tc_i += 1024;
    hs_iA += 256;
    hs_iB += 256;
  }
#undef GATES
#undef POLLSC
#undef HEADS
}

// ------------- post pass: obj head, sigma head, FK, normalize -------------
__global__ __launch_bounds__(256) void k_post(
    const bf16* __restrict__ Hseq, const bf16* __restrict__ Wo1b,
    const bf16* __restrict__ Wo2b, const bf16* __restrict__ Wvb,
    const float* __restrict__ bo1, const float* __restrict__ bo2,
    const float* __restrict__ bv,
    const float* __restrict__ Wfk, const float* __restrict__ bfk,
    const float* __restrict__ pm, const float* __restrict__ ps,
    const float* __restrict__ joints, float* __restrict__ out0,
    float* __restrict__ out3) {
  __shared__ bf16 u1buf[16][P1PAD];
  __shared__ float objbuf[16][3];
  __shared__ float jbuf[16][12];
  const int tid = threadIdx.x;
  const int wv = tid >> 6;
  const int ln = tid & 63;
  const int lr = ln & 15;
  const int lq = ln >> 4;

  bf16x8 wo1f[4][8];
  float bo1r[4];
  #pragma unroll
  for (int jn = 0; jn < 4; ++jn) {
    int n0 = wv * 64 + jn * 16;
    bo1r[jn] = bo1[n0 + lr];
    #pragma unroll
    for (int kt = 0; kt < 8; ++kt)
      wo1f[jn][kt] = *reinterpret_cast<const bf16x8*>(
          &Wo1b[(size_t)(n0 + lr) * 256 + kt * 32 + lq * 8]);
  }
  const int col = (wv - 1) * 16 + lr;
  bf16x8 wvf[8];
  float bvr = 0.f;
  if (wv >= 1) {
    #pragma unroll
    for (int kt = 0; kt < 8; ++kt)
      wvf[kt] = *reinterpret_cast<const bf16x8*>(
          &Wvb[(size_t)col * 256 + kt * 32 + lq * 8]);
    bvr = (col < 42) ? bv[col] : 0.f;
  }
  bf16x8 wo2f[8];
  if (wv == 0) {
    #pragma unroll
    for (int kt = 0; kt < 8; ++kt)
      wo2f[kt] = *reinterpret_cast<const bf16x8*>(
          &Wo2b[(size_t)lr * 256 + kt * 32 + lq * 8]);
  }

  for (int it = 0; it < 10; ++it) {
    int tt = blockIdx.x * 10 + it;
    size_t r0 = (size_t)tt * 16;
    bf16x8 ah[8];
    #pragma unroll
    for (int kt = 0; kt < 8; ++kt)
      ah[kt] = *reinterpret_cast<const bf16x8*>(&Hseq[(r0 + lr) * 256 + kt * 32 + lq * 8]);
    #pragma unroll
    for (int jn = 0; jn < 4; ++jn) {
      int n0 = wv * 64 + jn * 16;
      float bb = bo1r[jn];
      f32x4 acc = {bb, bb, bb, bb};
      #pragma unroll
      for (int kt = 0; kt < 8; ++kt)
        acc = __builtin_amdgcn_mfma_f32_16x16x32_bf16(ah[kt], wo1f[jn][kt], acc, 0, 0, 0);
      #pragma unroll
      for (int r = 0; r < 4; ++r)
        u1buf[lq * 4 + r][n0 + lr] = (bf16)fmaxf(acc[r], 0.f);
    }
    if (wv >= 1) {
      f32x4 acc = {bvr, bvr, bvr, bvr};
      #pragma unroll
      for (int kt = 0; kt < 8; ++kt)
        acc = __builtin_amdgcn_mfma_f32_16x16x32_bf16(ah[kt], wvf[kt], acc, 0, 0, 0);
      if (col < 42) {
        #pragma unroll
        for (int r = 0; r < 4; ++r) {
          float s = 0.05f + 0.45f * sigf(acc[r]);
          out3[(r0 + lq * 4 + r) * 42 + col] = __logf(s);
        }
      }
    }
    if (tid < 192) {
      int rr = tid / 12, d = tid % 12;
      jbuf[rr][d] = joints[(r0 + rr) * 12 + d];
    }
    __syncthreads();
    if (wv == 0) {
      bf16x8 ap[8];
      #pragma unroll
      for (int kt = 0; kt < 8; ++kt)
        ap[kt] = *reinterpret_cast<const bf16x8*>(&u1buf[lr][kt * 32 + lq * 8]);
      f32x4 acc = {0.f, 0.f, 0.f, 0.f};
      #pragma unroll
      for (int kt = 0; kt < 8; ++kt)
        acc = __builtin_amdgcn_mfma_f32_16x16x32_bf16(ap[kt], wo2f[kt], acc, 0, 0, 0);
      if (lr < 3) {
        #pragma unroll
        for (int r = 0; r < 4; ++r)
          objbuf[lq * 4 + r][lr] = acc[r] + bo2[lr];
      }
    }
    __syncthreads();
    for (int e = tid; e < 16 * 42; e += 256) {
      int rr = e / 42, pd = e % 42;
      float v;
      if (pd < 39) {
        float s = bfk[pd];
        #pragma unroll
        for (int d = 0; d < 12; ++d) s += jbuf[rr][d] * Wfk[pd * 12 + d];
        v = s;
      } else v = objbuf[rr][pd - 39];
      out0[(r0 + rr) * 42 + pd] = (v - pm[pd]) / ps[pd];
    }
    __syncthreads();
  }
}

extern "C" void kernel_launch(void* const* d_in, const int* in_sizes, int n_in,
                              void* d_out, int out_size, void* d_ws, size_t ws_size,
                              hipStream_t stream) {
  const float* z   = (const float*)d_in[0];
  const float* Whz = (const float*)d_in[1];
  const float* bhz = (const float*)d_in[2];
  const float* Wcz = (const float*)d_in[3];
  const float* bcz = (const float*)d_in[4];
  const float* Wih = (const float*)d_in[5];
  const float* Whh = (const float*)d_in[6];
  const float* bih = (const float*)d_in[7];
  const float* bhh = (const float*)d_in[8];
  const float* Wp1 = (const float*)d_in[9];
  const float* bp1 = (const float*)d_in[10];
  const float* Wp2 = (const float*)d_in[11];
  const float* bp2 = (const float*)d_in[12];
  const float* Wo1 = (const float*)d_in[13];
  const float* bo1 = (const float*)d_in[14];
  const float* Wo2 = (const float*)d_in[15];
  const float* bo2 = (const float*)d_in[16];
  const float* Wv  = (const float*)d_in[17];
  const float* bv  = (const float*)d_in[18];
  const float* Wfk = (const float*)d_in[19];
  const float* bfk = (const float*)d_in[20];
  const float* pm  = (const float*)d_in[21];
  const float* ps  = (const float*)d_in[22];
  const float* jlo = (const float*)d_in[23];
  const float* jhi = (const float*)d_in[24];
  const float* ddp = (const float*)d_in[25];

  char* ws = (char*)d_ws;
  float* tf    = (float*)(ws + OFF_TF);
  float* tconp = (float*)(ws + OFF_TCONP);
  float* zcp   = (float*)(ws + OFF_ZCP);
  float* h0    = (float*)(ws + OFF_H0);
  float* c0    = (float*)(ws + OFF_C0);
  bf16* Wcomb  = (bf16*)(ws + OFF_WCOMB);
  bf16* Wp1b   = (bf16*)(ws + OFF_WP1);
  bf16* Wp2b   = (bf16*)(ws + OFF_WP2);
  bf16* Wo1b   = (bf16*)(ws + OFF_WO1);
  bf16* Wo2b   = (bf16*)(ws + OFF_WO2);
  bf16* Wvb    = (bf16*)(ws + OFF_WV);
  u64* hxt     = (u64*)(ws + OFF_HX);
  bf16* Hseq   = (bf16*)(ws + OFF_HSEQ);

  float* out  = (float*)d_out;
  float* out0 = out;                 // graph_x_mu [B,T,42]
  float* outJ = out + 2150400;       // joint_traj [B,T,12]
  float* outA = out + 2764800;       // actions    [B,T,12]
  float* out3 = out + 3379200;       // log_sigma  [B,T,42]

  k_tfeat<<<11, 256, 0, stream>>>(tf);
  k_prep<<<2336, 256, 0, stream>>>(tf, Wih, z, bih, bhh, Whz, bhz, Wcz, bcz,
                                   tconp, zcp, h0, c0);
  k_cast<<<1744, 256, 0, stream>>>(Whh, Wih, Wp1, Wp2, Wo1, Wo2, Wv,
                                   Wcomb, Wp1b, Wp2b, Wo1b, Wo2b, Wvb);
  k_recur<<<32, 256, 0, stream>>>(zcp, tconp, h0, c0, Wcomb, Wp1b, Wp2b,
                                  bp1, bp2, jlo, jhi, ddp, hxt,
                                  Hseq, outJ, outA);
  k_post<<<320, 256, 0, stream>>>(Hseq, Wo1b, Wo2b, Wvb, bo1, bo2, bv,
                                  Wfk, bfk, pm, ps, outJ, out0, out3);
}

// Round 17
// 1077.147 us; speedup vs baseline: 1.9014x; 1.3268x over previous
//
#include <hip/hip_runtime.h>
#include <math.h>

#define B_ 256
#define T_ 200
#define H_ 256
#define DOF_ 12

typedef __bf16 bf16;
typedef __bf16 bf16x8 __attribute__((ext_vector_type(8)));
typedef float f32x4 __attribute__((ext_vector_type(4)));
typedef unsigned long long u64;

#define XK 288      // gate GEMM K: 256 h + 12 prev + 20 zero pad
#define XPAD 296
#define P1PAD 264

#define PI_D 3.14159265358979323846

// ---- workspace byte offsets (all 16B aligned) ----
#define OFF_TF     0u
#define OFF_TCONP  10400u
#define OFF_ZCP    829600u
#define OFF_H0     1878176u
#define OFF_C0     2140320u
#define OFF_WCOMB  2402464u
#define OFF_WP1    2992288u
#define OFF_WP2    3123360u
#define OFF_WO1    3131552u
#define OFF_WO2    3262624u
#define OFF_WV     3270816u
#define OFF_HX     3295392u    // slow (agent-atomic) exchange: 512KB
#define OFF_HXF    3819680u    // fast (same-XCD L2) exchange:  512KB
#define OFF_HSEQ   4343968u    // 256*200*256*2 = 26214400 (end ~30.6MB)

__device__ __forceinline__ float sigf(float x) { return 1.f / (1.f + __expf(-x)); }
__device__ __forceinline__ float tanh_f(float x) {
  float a = fabsf(x);
  float e = __expf(-2.f * a);
  float t = (1.f - e) * __builtin_amdgcn_rcpf(1.f + e);
  return x < 0.f ? -t : t;
}

// light barrier: order LDS, leave global ops in flight
#define LBAR() asm volatile("s_waitcnt lgkmcnt(0)\n\ts_barrier" ::: "memory")

// ---------------- time features [T,13] ----------------
__global__ void k_tfeat(float* tf) {
  int i = blockIdx.x * blockDim.x + threadIdx.x;
  if (i >= T_ * 13) return;
  int t = i / 13, j = i % 13;
  float tv = (float)t / 199.f;
  float v;
  if (j == 0) v = tv;
  else {
    int k = (j - 1) >> 1;
    float f = (float)(1 << k);
    double arg = 2.0 * PI_D * (double)f * (double)tv;
    v = (j & 1) ? (float)sin(arg) : (float)cos(arg);
  }
  tf[i] = v;
}

// ------------- precompute tconp, zcp, h0, c0 (lane-packed layouts) -------------
// tconp[t*1024 + u*4 + g]  (u = global unit 0..255)
// zcp[((bid64*256 + tid)*4 + g)*4 + r]  (bid64 = quarter*16 + grp)
__global__ void k_prep(const float* __restrict__ tf, const float* __restrict__ Wih,
                       const float* __restrict__ z,
                       const float* __restrict__ bih, const float* __restrict__ bhh,
                       const float* __restrict__ Whz, const float* __restrict__ bhz,
                       const float* __restrict__ Wcz, const float* __restrict__ bcz,
                       float* tconp, float* zcp, float* h0, float* c0) {
  int i = blockIdx.x * blockDim.x + threadIdx.x;
  if (i < 204800) {
    int g = i & 3, u = (i >> 2) & 255, t = i >> 10;
    int n = g * 256 + u;
    float s = 0.f;
    #pragma unroll
    for (int j = 0; j < 13; ++j) s += tf[t * 13 + j] * Wih[n * 89 + 76 + j];
    tconp[i] = s;
    return;
  }
  i -= 204800;
  if (i < 262144) {
    int r = i & 3, g = (i >> 2) & 3, tid = (i >> 4) & 255, bid = i >> 12;
    int quarter = bid >> 4, grp = bid & 15;
    int wv = tid >> 6, ln = tid & 63, lr = ln & 15, lq = (ln >> 4) & 3;
    int b = grp * 16 + lq * 4 + r;
    int n = g * 256 + 64 * quarter + 16 * wv + lr;
    float s = bih[n] + bhh[n];
    for (int k = 0; k < 64; ++k) s += z[b * 64 + k] * Wih[n * 89 + 12 + k];
    zcp[i] = s;
    return;
  }
  i -= 262144;
  if (i < 65536) {
    int b = i / 256, u = i % 256;
    float s = bhz[u];
    for (int k = 0; k < 64; ++k) s += z[b * 64 + k] * Whz[u * 64 + k];
    h0[i] = s;
    return;
  }
  i -= 65536;
  if (i < 65536) {
    int b = i / 256, u = i % 256;
    float s = bcz[u];
    for (int k = 0; k < 64; ++k) s += z[b * 64 + k] * Wcz[u * 64 + k];
    c0[i] = s;
  }
}

// ------------- bf16 weight casts -------------
__global__ void k_cast(const float* __restrict__ Whh, const float* __restrict__ Wih,
                       const float* __restrict__ Wp1, const float* __restrict__ Wp2,
                       const float* __restrict__ Wo1, const float* __restrict__ Wo2,
                       const float* __restrict__ Wv,
                       bf16* Wcomb, bf16* Wp1b, bf16* Wp2b, bf16* Wo1b,
                       bf16* Wo2b, bf16* Wvb) {
  int i = blockIdx.x * blockDim.x + threadIdx.x;
  if (i < 294912) {
    int n = i / XK, k = i % XK;
    float v = (k < 256) ? Whh[n * 256 + k]
            : ((k < 268) ? Wih[n * 89 + (k - 256)] : 0.f);
    Wcomb[i] = (bf16)v;
    return;
  }
  i -= 294912;
  if (i < 65536) { Wp1b[i] = (bf16)Wp1[i]; return; }
  i -= 65536;
  if (i < 4096) { int r = i / 256; Wp2b[i] = (bf16)((r < 12) ? Wp2[i] : 0.f); return; }
  i -= 4096;
  if (i < 65536) { Wo1b[i] = (bf16)Wo1[i]; return; }
  i -= 65536;
  if (i < 4096) { int r = i / 256; Wo2b[i] = (bf16)((r < 3) ? Wo2[i] : 0.f); return; }
  i -= 4096;
  if (i < 12288) { int r = i / 256; Wvb[i] = (bf16)((r < 42) ? Wv[i] : 0.f); }
}

// ------- recurrent LSTM: 64 blocks = 16 batch-groups x 4 unit-quarters -------
// 256 thr / 4 waves, 1 wave/SIMD. Gate weights (quarter) = 144 AGPRs/lane.
// Wp1+Wp2 in LDS. 3-partner tag-embedded u64 h exchange with DUAL transport:
// fast = volatile (sc0) stores/loads through the shared same-XCD L2 (valid
// only if partners co-located; self-validating tags detect it), slow = relaxed
// agent-scope atomics at the coherence point (always correct). Reader tries
// the fast window once, falls back permanently if tags never appear.
__global__ __launch_bounds__(256, 1) void k_recur(
    const float* __restrict__ zcp, const float* __restrict__ tconp,
    const float* __restrict__ h0, const float* __restrict__ c0,
    const bf16* __restrict__ Wcomb, const bf16* __restrict__ Wp1b,
    const bf16* __restrict__ Wp2b,
    const float* __restrict__ bp1, const float* __restrict__ bp2,
    const float* __restrict__ jlo, const float* __restrict__ jhi,
    const float* __restrict__ ddp,
    u64* hxt, u64* hxf,
    bf16* __restrict__ Hseq, float* __restrict__ outJ, float* __restrict__ outA) {
  __shared__ bf16 xbuf[16][XPAD];
  __shared__ bf16 w1[272][P1PAD];      // 0..255 Wp1, 256..271 Wp2
  __shared__ bf16 p1buf[16][P1PAD];
  const int tid = threadIdx.x;
  const int wv = tid >> 6, ln = tid & 63, lr = ln & 15, lq = ln >> 4;
  const int bid = blockIdx.x;
  const int quarter = bid >> 4, grp = bid & 15;   // partners: same grp, bid%8 equal
  const int b0 = grp * 16;
  const int u_gl = 64 * quarter + 16 * wv + lr;

  // ---- one-time LDS fills (stride 256) ----
  for (int i = tid; i < 272 * 32; i += 256) {
    int r = i >> 5, c8 = (i & 31) * 8;
    bf16x8 v = (r < 256)
      ? *reinterpret_cast<const bf16x8*>(&Wp1b[r * 256 + c8])
      : *reinterpret_cast<const bf16x8*>(&Wp2b[(r - 256) * 256 + c8]);
    *reinterpret_cast<bf16x8*>(&w1[r][c8]) = v;
  }
  for (int i = tid; i < 16 * XPAD; i += 256) {
    int r = i / XPAD, c = i % XPAD;
    float v = 0.f;
    if (c < 256) v = h0[(b0 + r) * 256 + c];
    else if (c < 268) {
      int d = c - 256;
      float lo = jlo[d], hi = jhi[d];
      v = (ddp[d] - 0.5f * (hi + lo)) / (0.5f * (hi - lo));
    }
    xbuf[r][c] = (bf16)v;
  }

  // ---- quarter's gate weights -> AGPRs (144 regs/lane) ----
  f32x4 wc[4][9];
  #pragma unroll
  for (int g = 0; g < 4; ++g)
    #pragma unroll
    for (int kt = 0; kt < 9; ++kt)
      wc[g][kt] = *reinterpret_cast<const f32x4*>(
          &Wcomb[(size_t)(g * 256 + u_gl) * XK + kt * 32 + lq * 8]);
  #pragma unroll
  for (int kt = 0; kt < 9; ++kt)
    asm volatile("" : "+a"(wc[0][kt]), "+a"(wc[1][kt]),
                      "+a"(wc[2][kt]), "+a"(wc[3][kt]));

  // ---- per-lane state ----
  float c_reg[4];
  #pragma unroll
  for (int r = 0; r < 4; ++r) c_reg[r] = c0[(b0 + lq * 4 + r) * 256 + u_gl];
  const int zc_i = (bid * 256 + tid) * 16;
  int tc_i = u_gl * 4;                              // += 1024 / step
  int hs_i = ((b0 + lq * 4) * T_) * 256 + u_gl;     // += 256 / step
  const int pw_i = (grp * 8 + quarter) * 512 + (16 * wv + lr) * 8 + lq * 2;
  const int ru = tid >> 2, rlq = tid & 3;
  const int rrow0 = rlq * 4;
  const int q1 = (quarter + 1) & 3, q2 = (quarter + 2) & 3, q3 = (quarter + 3) & 3;
  const int pr1 = (grp * 8 + q1) * 512 + ru * 8 + rlq * 2;
  const int pr2 = (grp * 8 + q2) * 512 + ru * 8 + rlq * 2;
  const int pr3 = (grp * 8 + q3) * 512 + ru * 8 + rlq * 2;

  float bp1r[4];
  #pragma unroll
  for (int jn = 0; jn < 4; ++jn) bp1r[jn] = bp1[64 * wv + 16 * jn + lr];
  float bp2r = 0.f, ddr = 0.f, lor = -1.f, hir = 1.f;
  if (lr < 12) { bp2r = bp2[lr]; ddr = ddp[lr]; lor = jlo[lr]; hir = jhi[lr]; }
  const float jmr = 0.5f * (hir + lor), jrr = 0.5f * (hir - lor);

  __syncthreads();
  bool dead = false;
  bool slowmode = false;

  for (int t = 0; t < T_; ++t) {
    // ---- issue zc + tcon loads early (L2-resident; hidden under 36 MFMA) ----
    f32x4 zc[4], tcv;
    #pragma unroll
    for (int g = 0; g < 4; ++g)
      zc[g] = *reinterpret_cast<const f32x4*>(zcp + zc_i + g * 4);
    tcv = *reinterpret_cast<const f32x4*>(tconp + tc_i);
    tc_i += 1024;

    // ---- gates: kt-outer, AGPR weights, zero-init C ----
    f32x4 ac[4];
    #pragma unroll
    for (int g = 0; g < 4; ++g) ac[g] = (f32x4){0.f, 0.f, 0.f, 0.f};
    #pragma unroll
    for (int kt = 0; kt < 9; ++kt) {
      bf16x8 a = *reinterpret_cast<const bf16x8*>(&xbuf[lr][kt * 32 + lq * 8]);
      asm volatile("" : "+a"(wc[0][kt]), "+a"(wc[1][kt]),
                        "+a"(wc[2][kt]), "+a"(wc[3][kt]));
      #pragma unroll
      for (int g = 0; g < 4; ++g)
        ac[g] = __builtin_amdgcn_mfma_f32_16x16x32_bf16(
            a, __builtin_bit_cast(bf16x8, wc[g][kt]), ac[g], 0, 0, 0);
    }
    #pragma unroll
    for (int g = 0; g < 4; ++g) ac[g] += zc[g] + tcv[g];
    LBAR();  // all xbuf reads done before h overwrite

    // ---- LSTM elementwise + publish (tag-embedded, fast + slow) ----
    const unsigned int want = t + 1;
    bf16 hb[4];
    unsigned short s4[4];
    #pragma unroll
    for (int r = 0; r < 4; ++r) {
      float cn = sigf(ac[1][r]) * c_reg[r] + sigf(ac[0][r]) * tanh_f(ac[2][r]);
      float hn = sigf(ac[3][r]) * tanh_f(cn);
      c_reg[r] = cn;
      bf16 h = (bf16)hn;
      hb[r] = h;
      s4[r] = __builtin_bit_cast(unsigned short, h);
    }
    {
      u64 q0 = ((u64)want << 32) | (u64)s4[0] | ((u64)s4[1] << 16);
      u64 qq1 = ((u64)want << 32) | (u64)s4[2] | ((u64)s4[3] << 16);
      int pwi = pw_i + (t & 1) * 2048;
      // fast same-XCD L2 copy (write-through; sc0 readers see it)
      volatile u64* f = (volatile u64*)(hxf + pwi);
      f[0] = q0;
      f[1] = qq1;
      // slow coherent-point copy (always correct)
      __hip_atomic_store(hxt + pwi, q0, __ATOMIC_RELAXED, __HIP_MEMORY_SCOPE_AGENT);
      __hip_atomic_store(hxt + pwi + 1, qq1, __ATOMIC_RELAXED, __HIP_MEMORY_SCOPE_AGENT);
    }
    // own h -> xbuf + Hseq (in the poll shadow)
    #pragma unroll
    for (int r = 0; r < 4; ++r) {
      xbuf[lq * 4 + r][u_gl] = hb[r];
      Hseq[hs_i + r * (T_ * 256)] = hb[r];
    }
    hs_i += 256;

    // ---- poll: fast window first (sticky), slow fallback ----
    u64 pa0, pa1, pb0, pb1, pc0, pc1;
    {
      const int so = (t & 1) * 2048;
      if (!slowmode) {
        int fg = 64;
        for (;;) {
          volatile const u64* f1 = (volatile const u64*)(hxf + pr1 + so);
          volatile const u64* f2 = (volatile const u64*)(hxf + pr2 + so);
          volatile const u64* f3 = (volatile const u64*)(hxf + pr3 + so);
          pa0 = f1[0]; pa1 = f1[1];
          pb0 = f2[0]; pb1 = f2[1];
          pc0 = f3[0]; pc1 = f3[1];
          int ok = ((unsigned)(pa0 >> 32) == want) & ((unsigned)(pa1 >> 32) == want) &
                   ((unsigned)(pb0 >> 32) == want) & ((unsigned)(pb1 >> 32) == want) &
                   ((unsigned)(pc0 >> 32) == want) & ((unsigned)(pc1 >> 32) == want);
          if (__all(ok)) break;
          if (--fg == 0) { slowmode = true; break; }
        }
      }
      if (slowmode) {
        int guard = 1 << 16;
        for (;;) {
          pa0 = __hip_atomic_load(hxt + pr1 + so, __ATOMIC_RELAXED, __HIP_MEMORY_SCOPE_AGENT);
          pa1 = __hip_atomic_load(hxt + pr1 + so + 1, __ATOMIC_RELAXED, __HIP_MEMORY_SCOPE_AGENT);
          pb0 = __hip_atomic_load(hxt + pr2 + so, __ATOMIC_RELAXED, __HIP_MEMORY_SCOPE_AGENT);
          pb1 = __hip_atomic_load(hxt + pr2 + so + 1, __ATOMIC_RELAXED, __HIP_MEMORY_SCOPE_AGENT);
          pc0 = __hip_atomic_load(hxt + pr3 + so, __ATOMIC_RELAXED, __HIP_MEMORY_SCOPE_AGENT);
          pc1 = __hip_atomic_load(hxt + pr3 + so + 1, __ATOMIC_RELAXED, __HIP_MEMORY_SCOPE_AGENT);
          int ok = ((unsigned)(pa0 >> 32) == want) & ((unsigned)(pa1 >> 32) == want) &
                   ((unsigned)(pb0 >> 32) == want) & ((unsigned)(pb1 >> 32) == want) &
                   ((unsigned)(pc0 >> 32) == want) & ((unsigned)(pc1 >> 32) == want);
          if (__all(ok)) break;
          if (dead || --guard == 0) { dead = true; break; }
        }
      }
    }
    {
      int col1 = 64 * q1 + ru, col2 = 64 * q2 + ru, col3 = 64 * q3 + ru;
      xbuf[rrow0 + 0][col1] = __builtin_bit_cast(bf16, (unsigned short)(pa0));
      xbuf[rrow0 + 1][col1] = __builtin_bit_cast(bf16, (unsigned short)(pa0 >> 16));
      xbuf[rrow0 + 2][col1] = __builtin_bit_cast(bf16, (unsigned short)(pa1));
      xbuf[rrow0 + 3][col1] = __builtin_bit_cast(bf16, (unsigned short)(pa1 >> 16));
      xbuf[rrow0 + 0][col2] = __builtin_bit_cast(bf16, (unsigned short)(pb0));
      xbuf[rrow0 + 1][col2] = __builtin_bit_cast(bf16, (unsigned short)(pb0 >> 16));
      xbuf[rrow0 + 2][col2] = __builtin_bit_cast(bf16, (unsigned short)(pb1));
      xbuf[rrow0 + 3][col2] = __builtin_bit_cast(bf16, (unsigned short)(pb1 >> 16));
      xbuf[rrow0 + 0][col3] = __builtin_bit_cast(bf16, (unsigned short)(pc0));
      xbuf[rrow0 + 1][col3] = __builtin_bit_cast(bf16, (unsigned short)(pc0 >> 16));
      xbuf[rrow0 + 2][col3] = __builtin_bit_cast(bf16, (unsigned short)(pc1));
      xbuf[rrow0 + 3][col3] = __builtin_bit_cast(bf16, (unsigned short)(pc1 >> 16));
    }
    LBAR();  // full h_new visible

    // ---- p1 = relu(h_new @ Wp1^T + bp1): wave owns 64 cols, kt-outer ----
    {
      f32x4 pa[4];
      #pragma unroll
      for (int jn = 0; jn < 4; ++jn)
        pa[jn] = (f32x4){bp1r[jn], bp1r[jn], bp1r[jn], bp1r[jn]};
      #pragma unroll
      for (int kt = 0; kt < 8; ++kt) {
        bf16x8 av = *reinterpret_cast<const bf16x8*>(&xbuf[lr][kt * 32 + lq * 8]);
        #pragma unroll
        for (int jn = 0; jn < 4; ++jn) {
          bf16x8 bv = *reinterpret_cast<const bf16x8*>(
              &w1[64 * wv + 16 * jn + lr][kt * 32 + lq * 8]);
          pa[jn] = __builtin_amdgcn_mfma_f32_16x16x32_bf16(av, bv, pa[jn], 0, 0, 0);
        }
      }
      #pragma unroll
      for (int jn = 0; jn < 4; ++jn)
        #pragma unroll
        for (int r = 0; r < 4; ++r)
          p1buf[lq * 4 + r][64 * wv + 16 * jn + lr] = (bf16)fmaxf(pa[jn][r], 0.f);
    }
    LBAR();  // p1 visible

    // ---- action head on wave 0 (redundant across quarters; writes gated) ----
    if (wv == 0) {
      f32x4 acc = {0.f, 0.f, 0.f, 0.f};
      #pragma unroll
      for (int kt = 0; kt < 8; ++kt) {
        bf16x8 ap = *reinterpret_cast<const bf16x8*>(&p1buf[lr][kt * 32 + lq * 8]);
        bf16x8 w2 = *reinterpret_cast<const bf16x8*>(&w1[256 + lr][kt * 32 + lq * 8]);
        acc = __builtin_amdgcn_mfma_f32_16x16x32_bf16(ap, w2, acc, 0, 0, 0);
      }
      if (lr < 12) {
        #pragma unroll
        for (int r = 0; r < 4; ++r) {
          int b = lq * 4 + r;
          float act = tanh_f(acc[r] + bp2r);
          float curp = act * 0.25f + ddr;   // TRACK_ALPHA = 1
          float cl = fminf(fmaxf(curp, lor), hir);
          if (quarter == 0) {
            size_t o = ((size_t)(b0 + b) * T_ + t) * 12 + lr;
            outA[o] = act;
            outJ[o] = curp;
          }
          xbuf[b][256 + lr] = (bf16)((cl - jmr) / jrr);
        }
      }
    }
    LBAR();  // prev_norm visible for next step
  }
}

// ------------- post pass: obj head, sigma head, FK, normalize -------------
__global__ __launch_bounds__(256) void k_post(
    const bf16* __restrict__ Hseq, const bf16* __restrict__ Wo1b,
    const bf16* __restrict__ Wo2b, const bf16* __restrict__ Wvb,
    const float* __restrict__ bo1, const float* __restrict__ bo2,
    const float* __restrict__ bv,
    const float* __restrict__ Wfk, const float* __restrict__ bfk,
    const float* __restrict__ pm, const float* __restrict__ ps,
    const float* __restrict__ joints, float* __restrict__ out0,
    float* __restrict__ out3) {
  __shared__ bf16 u1buf[16][P1PAD];
  __shared__ float objbuf[16][3];
  __shared__ float jbuf[16][12];
  const int tid = threadIdx.x;
  const int wv = tid >> 6;
  const int ln = tid & 63;
  const int lr = ln & 15;
  const int lq = ln >> 4;

  bf16x8 wo1f[4][8];
  float bo1r[4];
  #pragma unroll
  for (int jn = 0; jn < 4; ++jn) {
    int n0 = wv * 64 + jn * 16;
    bo1r[jn] = bo1[n0 + lr];
    #pragma unroll
    for (int kt = 0; kt < 8; ++kt)
      wo1f[jn][kt] = *reinterpret_cast<const bf16x8*>(
          &Wo1b[(size_t)(n0 + lr) * 256 + kt * 32 + lq * 8]);
  }
  const int col = (wv - 1) * 16 + lr;
  bf16x8 wvf[8];
  float bvr = 0.f;
  if (wv >= 1) {
    #pragma unroll
    for (int kt = 0; kt < 8; ++kt)
      wvf[kt] = *reinterpret_cast<const bf16x8*>(
          &Wvb[(size_t)col * 256 + kt * 32 + lq * 8]);
    bvr = (col < 42) ? bv[col] : 0.f;
  }
  bf16x8 wo2f[8];
  if (wv == 0) {
    #pragma unroll
    for (int kt = 0; kt < 8; ++kt)
      wo2f[kt] = *reinterpret_cast<const bf16x8*>(
          &Wo2b[(size_t)lr * 256 + kt * 32 + lq * 8]);
  }

  for (int it = 0; it < 10; ++it) {
    int tt = blockIdx.x * 10 + it;
    size_t r0 = (size_t)tt * 16;
    bf16x8 ah[8];
    #pragma unroll
    for (int kt = 0; kt < 8; ++kt)
      ah[kt] = *reinterpret_cast<const bf16x8*>(&Hseq[(r0 + lr) * 256 + kt * 32 + lq * 8]);
    #pragma unroll
    for (int jn = 0; jn < 4; ++jn) {
      int n0 = wv * 64 + jn * 16;
      float bb = bo1r[jn];
      f32x4 acc = {bb, bb, bb, bb};
      #pragma unroll
      for (int kt = 0; kt < 8; ++kt)
        acc = __builtin_amdgcn_mfma_f32_16x16x32_bf16(ah[kt], wo1f[jn][kt], acc, 0, 0, 0);
      #pragma unroll
      for (int r = 0; r < 4; ++r)
        u1buf[lq * 4 + r][n0 + lr] = (bf16)fmaxf(acc[r], 0.f);
    }
    if (wv >= 1) {
      f32x4 acc = {bvr, bvr, bvr, bvr};
      #pragma unroll
      for (int kt = 0; kt < 8; ++kt)
        acc = __builtin_amdgcn_mfma_f32_16x16x32_bf16(ah[kt], wvf[kt], acc, 0, 0, 0);
      if (col < 42) {
        #pragma unroll
        for (int r = 0; r < 4; ++r) {
          float s = 0.05f + 0.45f * sigf(acc[r]);
          out3[(r0 + lq * 4 + r) * 42 + col] = __logf(s);
        }
      }
    }
    if (tid < 192) {
      int rr = tid / 12, d = tid % 12;
      jbuf[rr][d] = joints[(r0 + rr) * 12 + d];
    }
    __syncthreads();
    if (wv == 0) {
      bf16x8 ap[8];
      #pragma unroll
      for (int kt = 0; kt < 8; ++kt)
        ap[kt] = *reinterpret_cast<const bf16x8*>(&u1buf[lr][kt * 32 + lq * 8]);
      f32x4 acc = {0.f, 0.f, 0.f, 0.f};
      #pragma unroll
      for (int kt = 0; kt < 8; ++kt)
        acc = __builtin_amdgcn_mfma_f32_16x16x32_bf16(ap[kt], wo2f[kt], acc, 0, 0, 0);
      if (lr < 3) {
        #pragma unroll
        for (int r = 0; r < 4; ++r)
          objbuf[lq * 4 + r][lr] = acc[r] + bo2[lr];
      }
    }
    __syncthreads();
    for (int e = tid; e < 16 * 42; e += 256) {
      int rr = e / 42, pd = e % 42;
      float v;
      if (pd < 39) {
        float s = bfk[pd];
        #pragma unroll
        for (int d = 0; d < 12; ++d) s += jbuf[rr][d] * Wfk[pd * 12 + d];
        v = s;
      } else v = objbuf[rr][pd - 39];
      out0[(r0 + rr) * 42 + pd] = (v - pm[pd]) / ps[pd];
    }
    __syncthreads();
  }
}

extern "C" void kernel_launch(void* const* d_in, const int* in_sizes, int n_in,
                              void* d_out, int out_size, void* d_ws, size_t ws_size,
                              hipStream_t stream) {
  const float* z   = (const float*)d_in[0];
  const float* Whz = (const float*)d_in[1];
  const float* bhz = (const float*)d_in[2];
  const float* Wcz = (const float*)d_in[3];
  const float* bcz = (const float*)d_in[4];
  const float* Wih = (const float*)d_in[5];
  const float* Whh = (const float*)d_in[6];
  const float* bih = (const float*)d_in[7];
  const float* bhh = (const float*)d_in[8];
  const float* Wp1 = (const float*)d_in[9];
  const float* bp1 = (const float*)d_in[10];
  const float* Wp2 = (const float*)d_in[11];
  const float* bp2 = (const float*)d_in[12];
  const float* Wo1 = (const float*)d_in[13];
  const float* bo1 = (const float*)d_in[14];
  const float* Wo2 = (const float*)d_in[15];
  const float* bo2 = (const float*)d_in[16];
  const float* Wv  = (const float*)d_in[17];
  const float* bv  = (const float*)d_in[18];
  const float* Wfk = (const float*)d_in[19];
  const float* bfk = (const float*)d_in[20];
  const float* pm  = (const float*)d_in[21];
  const float* ps  = (const float*)d_in[22];
  const float* jlo = (const float*)d_in[23];
  const float* jhi = (const float*)d_in[24];
  const float* ddp = (const float*)d_in[25];

  char* ws = (char*)d_ws;
  float* tf    = (float*)(ws + OFF_TF);
  float* tconp = (float*)(ws + OFF_TCONP);
  float* zcp   = (float*)(ws + OFF_ZCP);
  float* h0    = (float*)(ws + OFF_H0);
  float* c0    = (float*)(ws + OFF_C0);
  bf16* Wcomb  = (bf16*)(ws + OFF_WCOMB);
  bf16* Wp1b   = (bf16*)(ws + OFF_WP1);
  bf16* Wp2b   = (bf16*)(ws + OFF_WP2);
  bf16* Wo1b   = (bf16*)(ws + OFF_WO1);
  bf16* Wo2b   = (bf16*)(ws + OFF_WO2);
  bf16* Wvb    = (bf16*)(ws + OFF_WV);
  u64* hxt     = (u64*)(ws + OFF_HX);
  u64* hxf     = (u64*)(ws + OFF_HXF);
  bf16* Hseq   = (bf16*)(ws + OFF_HSEQ);

  float* out  = (float*)d_out;
  float* out0 = out;                 // graph_x_mu [B,T,42]
  float* outJ = out + 2150400;       // joint_traj [B,T,12]
  float* outA = out + 2764800;       // actions    [B,T,12]
  float* out3 = out + 3379200;       // log_sigma  [B,T,42]

  k_tfeat<<<11, 256, 0, stream>>>(tf);
  k_prep<<<2336, 256, 0, stream>>>(tf, Wih, z, bih, bhh, Whz, bhz, Wcz, bcz,
                                   tconp, zcp, h0, c0);
  k_cast<<<1744, 256, 0, stream>>>(Whh, Wih, Wp1, Wp2, Wo1, Wo2, Wv,
                                   Wcomb, Wp1b, Wp2b, Wo1b, Wo2b, Wvb);
  k_recur<<<64, 256, 0, stream>>>(zcp, tconp, h0, c0, Wcomb, Wp1b, Wp2b,
                                  bp1, bp2, jlo, jhi, ddp, hxt, hxf,
                                  Hseq, outJ, outA);
  k_post<<<320, 256, 0, stream>>>(Hseq, Wo1b, Wo2b, Wvb, bo1, bo2, bv,
                                  Wfk, bfk, pm, ps, outJ, out0, out3);
}